// Round 1
// baseline (320.172 us; speedup 1.0000x reference)
//
#include <hip/hip_runtime.h>

// EnocoderBlock: x -> MHA -> +res,LN -> FFN -> +res,LN
// B=2, S=2048, D=1024, H=16, DK=64, DFF=4096. All GEMMs in bf16 MFMA (16x16x32),
// fp32 accum; softmax/LN/residual in fp32.

typedef float  f32x4  __attribute__((ext_vector_type(4)));
typedef __bf16 bf16x8 __attribute__((ext_vector_type(8)));
typedef __bf16 bf16x4 __attribute__((ext_vector_type(4)));

#define DEVI static __device__ __forceinline__

DEVI f32x4 mfma16(bf16x8 a, bf16x8 b, f32x4 c) {
    return __builtin_amdgcn_mfma_f32_16x16x32_bf16(a, b, c, 0, 0, 0);
}

// async global->LDS, 16B per lane. lds dest must be wave-uniform (HW adds lane*16).
DEVI void gll16(const void* g, void* l) {
    __builtin_amdgcn_global_load_lds(
        (__attribute__((address_space(1))) void*)g,
        (__attribute__((address_space(3))) void*)l, 16, 0, 0);
}

DEVI __bf16 f2bf(float f) { return (__bf16)f; }

// ---------------------------------------------------------------- utilities
__global__ void init_flag_kernel(int* f) { *f = 0; }

__global__ void mask_scan_kernel(const float* __restrict__ m, int* __restrict__ flag) {
    size_t i = (size_t)blockIdx.x * 256 + threadIdx.x;
    const float4* p = (const float4*)m;
    float4 a = p[i * 2], b = p[i * 2 + 1];
    bool nz = a.x != 0.f || a.y != 0.f || a.z != 0.f || a.w != 0.f ||
              b.x != 0.f || b.y != 0.f || b.z != 0.f || b.w != 0.f;
    if (__ballot(nz)) { if ((threadIdx.x & 63) == 0) atomicOr(flag, 1); }
}

__global__ void cast_bf16_kernel(const float* __restrict__ in, __bf16* __restrict__ out, int n8) {
    int i = blockIdx.x * 256 + threadIdx.x;
    if (i >= n8) return;
    const float4* p = (const float4*)in + (size_t)i * 2;
    float4 a = p[0], b = p[1];
    bf16x8 o = { (__bf16)a.x, (__bf16)a.y, (__bf16)a.z, (__bf16)a.w,
                 (__bf16)b.x, (__bf16)b.y, (__bf16)b.z, (__bf16)b.w };
    *(bf16x8*)(out + (size_t)i * 8) = o;
}

// ------------------------------------------------- residual add + LayerNorm
// out1 = alpha*(v-mean)/sqrt(var+eps)+gamma, v = X+Y. Writes f32 and optional bf16.
__global__ __launch_bounds__(256) void add_ln_kernel(
    const float* __restrict__ X, const float* __restrict__ Y,
    const float* __restrict__ alphap, const float* __restrict__ gammap,
    float* __restrict__ outF, __bf16* __restrict__ outB) {
    const int tid = threadIdx.x, lane = tid & 63, wid = tid >> 6;
    const size_t base = (size_t)blockIdx.x * 1024 + tid * 4;
    float4 xv = *(const float4*)&X[base];
    float4 yv = *(const float4*)&Y[base];
    float vx = xv.x + yv.x, vy = xv.y + yv.y, vz = xv.z + yv.z, vw = xv.w + yv.w;
    float s = vx + vy + vz + vw;
    #pragma unroll
    for (int o = 32; o; o >>= 1) s += __shfl_xor(s, o);
    __shared__ float red[4];
    if (lane == 0) red[wid] = s;
    __syncthreads();
    float mean = (red[0] + red[1] + red[2] + red[3]) * (1.0f / 1024.0f);
    float dx = vx - mean, dy = vy - mean, dz = vz - mean, dw = vw - mean;
    float s2 = dx * dx + dy * dy + dz * dz + dw * dw;
    #pragma unroll
    for (int o = 32; o; o >>= 1) s2 += __shfl_xor(s2, o);
    __syncthreads();
    if (lane == 0) red[wid] = s2;
    __syncthreads();
    float var = (red[0] + red[1] + red[2] + red[3]) * (1.0f / 1024.0f);
    float rstd = rsqrtf(var + 1e-6f);
    float a = alphap[0], g = gammap[0];
    float4 o4 = { a * dx * rstd + g, a * dy * rstd + g, a * dz * rstd + g, a * dw * rstd + g };
    *(float4*)&outF[base] = o4;
    if (outB) {
        bf16x4 ob = { f2bf(o4.x), f2bf(o4.y), f2bf(o4.z), f2bf(o4.w) };
        *(bf16x4*)&outB[base] = ob;
    }
}

// --------------------------------------------------------------- GEMM core
// C[m,n] = sum_k A[m,k]*W[n,k] + bias[n].  BM=128, BK=64, 4 waves (2x2).
// LDS XOR-8 swizzle: LDS(row,c) holds global chunk c^(row&7); staged with
// pre-swizzled global source + linear global_load_lds dest (G21).
// MODE 0: f32 out [M,N].  MODE 1: relu -> bf16 out [M,N].
template <int N, int K, int BN, int MODE>
__global__ __launch_bounds__(256, 2) void gemm_bt_kernel(
    const __bf16* __restrict__ A, const __bf16* __restrict__ W,
    const float* __restrict__ bias, void* __restrict__ outp) {
    constexpr int WN = BN / 2;
    constexpr int NI = WN / 16;
    __shared__ __bf16 lsA[128 * 64];
    __shared__ __bf16 lsB[BN * 64];
    const int tid = threadIdx.x, wid = tid >> 6, lane = tid & 63;
    const int wr = wid >> 1, wc = wid & 1, l15 = lane & 15, hi = lane >> 4;
    const int m0 = blockIdx.y * 128, n0 = blockIdx.x * BN;
    f32x4 acc[4][NI] = {};
    for (int kt = 0; kt < K / 64; ++kt) {
        #pragma unroll
        for (int i = 0; i < 4; ++i) {
            int row = wid * 32 + i * 8 + (lane >> 3);
            gll16(A + (size_t)(m0 + row) * K + kt * 64 + ((lane & 7) ^ (row & 7)) * 8,
                  &lsA[(wid * 32 + i * 8) * 64]);
        }
        #pragma unroll
        for (int i = 0; i < BN / 32; ++i) {
            int row = wid * (BN / 4) + i * 8 + (lane >> 3);
            gll16(W + (size_t)(n0 + row) * K + kt * 64 + ((lane & 7) ^ (row & 7)) * 8,
                  &lsB[(wid * (BN / 4) + i * 8) * 64]);
        }
        __syncthreads();
        #pragma unroll
        for (int s = 0; s < 2; ++s) {
            bf16x8 af[4], bfv[NI];
            #pragma unroll
            for (int mi = 0; mi < 4; ++mi) {
                int row = wr * 64 + mi * 16 + l15;
                af[mi] = *(const bf16x8*)&lsA[row * 64 + (((s * 4 + hi) ^ (row & 7)) * 8)];
            }
            #pragma unroll
            for (int ni = 0; ni < NI; ++ni) {
                int row = wc * WN + ni * 16 + l15;
                bfv[ni] = *(const bf16x8*)&lsB[row * 64 + (((s * 4 + hi) ^ (row & 7)) * 8)];
            }
            #pragma unroll
            for (int mi = 0; mi < 4; ++mi)
                #pragma unroll
                for (int ni = 0; ni < NI; ++ni)
                    acc[mi][ni] = mfma16(af[mi], bfv[ni], acc[mi][ni]);
        }
        __syncthreads();
    }
    #pragma unroll
    for (int ni = 0; ni < NI; ++ni) {
        int col = n0 + wc * WN + ni * 16 + l15;
        float bv = bias[col];
        #pragma unroll
        for (int mi = 0; mi < 4; ++mi) {
            int rowb = m0 + wr * 64 + mi * 16 + hi * 4;
            #pragma unroll
            for (int r = 0; r < 4; ++r) {
                float v = acc[mi][ni][r] + bv;
                if (MODE == 0) {
                    ((float*)outp)[(size_t)(rowb + r) * N + col] = v;
                } else {
                    v = fmaxf(v, 0.f);
                    ((__bf16*)outp)[(size_t)(rowb + r) * N + col] = f2bf(v);
                }
            }
        }
    }
}

// QKV fused GEMM (N=K=1024, BN=128), z picks {Q,K,V}.
// Q: *(0.125*log2e), layout [B,H,S,DK]. K: [B,H,S,DK]. V: transposed [B,H,DK,S].
__global__ __launch_bounds__(256, 2) void gemm_qkv_kernel(
    const __bf16* __restrict__ A,
    const __bf16* __restrict__ wq, const __bf16* __restrict__ wk, const __bf16* __restrict__ wv,
    const float* __restrict__ bq, const float* __restrict__ bk, const float* __restrict__ bv,
    __bf16* __restrict__ q, __bf16* __restrict__ k, __bf16* __restrict__ vt) {
    constexpr int K = 1024;
    const int z = blockIdx.z;
    const __bf16* W = (z == 0) ? wq : (z == 1) ? wk : wv;
    const float* bias = (z == 0) ? bq : (z == 1) ? bk : bv;
    __shared__ __bf16 lsA[128 * 64];
    __shared__ __bf16 lsB[128 * 64];
    const int tid = threadIdx.x, wid = tid >> 6, lane = tid & 63;
    const int wr = wid >> 1, wc = wid & 1, l15 = lane & 15, hi = lane >> 4;
    const int m0 = blockIdx.y * 128, n0 = blockIdx.x * 128;
    f32x4 acc[4][4] = {};
    for (int kt = 0; kt < K / 64; ++kt) {
        #pragma unroll
        for (int i = 0; i < 4; ++i) {
            int row = wid * 32 + i * 8 + (lane >> 3);
            gll16(A + (size_t)(m0 + row) * K + kt * 64 + ((lane & 7) ^ (row & 7)) * 8,
                  &lsA[(wid * 32 + i * 8) * 64]);
            gll16(W + (size_t)(n0 + row) * K + kt * 64 + ((lane & 7) ^ (row & 7)) * 8,
                  &lsB[(wid * 32 + i * 8) * 64]);
        }
        __syncthreads();
        #pragma unroll
        for (int s = 0; s < 2; ++s) {
            bf16x8 af[4], bfv[4];
            #pragma unroll
            for (int mi = 0; mi < 4; ++mi) {
                int row = wr * 64 + mi * 16 + l15;
                af[mi] = *(const bf16x8*)&lsA[row * 64 + (((s * 4 + hi) ^ (row & 7)) * 8)];
            }
            #pragma unroll
            for (int ni = 0; ni < 4; ++ni) {
                int row = wc * 64 + ni * 16 + l15;
                bfv[ni] = *(const bf16x8*)&lsB[row * 64 + (((s * 4 + hi) ^ (row & 7)) * 8)];
            }
            #pragma unroll
            for (int mi = 0; mi < 4; ++mi)
                #pragma unroll
                for (int ni = 0; ni < 4; ++ni)
                    acc[mi][ni] = mfma16(af[mi], bfv[ni], acc[mi][ni]);
        }
        __syncthreads();
    }
    const float scale = (z == 0) ? 0.125f * 1.4426950408889634f : 1.0f;
    #pragma unroll
    for (int ni = 0; ni < 4; ++ni) {
        int col = n0 + wc * 64 + ni * 16 + l15;
        int h = col >> 6, dk = col & 63;
        float bvv = bias[col];
        #pragma unroll
        for (int mi = 0; mi < 4; ++mi) {
            int rowb = m0 + wr * 64 + mi * 16 + hi * 4;
            int b_ = rowb >> 11, sb = rowb & 2047;
            if (z < 2) {
                __bf16* dst = (z == 0) ? q : k;
                #pragma unroll
                for (int r = 0; r < 4; ++r)
                    dst[((size_t)(b_ * 16 + h) * 2048 + sb + r) * 64 + dk] =
                        f2bf((acc[mi][ni][r] + bvv) * scale);
            } else {
                bf16x4 o = { f2bf(acc[mi][ni][0] + bvv), f2bf(acc[mi][ni][1] + bvv),
                             f2bf(acc[mi][ni][2] + bvv), f2bf(acc[mi][ni][3] + bvv) };
                *(bf16x4*)&vt[((size_t)(b_ * 16 + h) * 64 + dk) * 2048 + sb] = o;
            }
        }
    }
}

// ---------------------------------------------------------- flash attention
// grid (S/64, B*H). 4 waves x 16 q-rows. kv-tile 128. Q prescaled by 0.125*log2e
// (softmax in exp2 domain). ctx^T accumulated (D[m=dk][n=q]) so the online
// rescale factor is one scalar per lane.
__global__ __launch_bounds__(256, 2) void flash_attn_kernel(
    const __bf16* __restrict__ Q, const __bf16* __restrict__ Kx,
    const __bf16* __restrict__ VT, const float* __restrict__ mask,
    const int* __restrict__ mflag, __bf16* __restrict__ ctx) {
    __shared__ __bf16 Kl[128 * 64];
    __shared__ __bf16 Vl[64 * 128];
    __shared__ __bf16 Pl[4][16 * 128];
    const int tid = threadIdx.x, wid = tid >> 6, lane = tid & 63;
    const int l15 = lane & 15, hi = lane >> 4;
    const int bh = blockIdx.y, qt = blockIdx.x;
    const int qloc = qt * 64 + wid * 16 + l15;
    const size_t qbase = ((size_t)bh * 2048 + qloc) * 64;
    bf16x8 qf0 = *(const bf16x8*)&Q[qbase + hi * 8];
    bf16x8 qf1 = *(const bf16x8*)&Q[qbase + 32 + hi * 8];
    f32x4 ctxT[4] = {};
    float m0r = -1e30f, m1r = -1e30f, m2r = -1e30f, m3r = -1e30f;
    float l0r = 0.f, l1r = 0.f, l2r = 0.f, l3r = 0.f;
    const bool useMask = (*mflag != 0);

    for (int t = 0; t < 16; ++t) {
        #pragma unroll
        for (int i = 0; i < 4; ++i) {  // K tile [128 k][64 dk]
            int row = wid * 32 + i * 8 + (lane >> 3);
            gll16(&Kx[((size_t)bh * 2048 + t * 128 + row) * 64 + ((lane & 7) ^ (row & 7)) * 8],
                  &Kl[(wid * 32 + i * 8) * 64]);
        }
        #pragma unroll
        for (int i = 0; i < 4; ++i) {  // V^T tile [64 dk][128 k]
            int row = wid * 16 + i * 4 + hi;
            gll16(&VT[((size_t)bh * 64 + row) * 2048 + t * 128 + (l15 ^ (row & 7)) * 8],
                  &Vl[(wid * 16 + i * 4) * 128]);
        }
        __syncthreads();

        f32x4 sc[8];
        #pragma unroll
        for (int nf = 0; nf < 8; ++nf) {  // QK^T: D[m=q16][n=k128]
            int krow = nf * 16 + l15;
            bf16x8 kb0 = *(const bf16x8*)&Kl[krow * 64 + ((hi ^ (krow & 7)) * 8)];
            bf16x8 kb1 = *(const bf16x8*)&Kl[krow * 64 + (((4 + hi) ^ (krow & 7)) * 8)];
            f32x4 zz = {};
            zz = mfma16(qf0, kb0, zz);
            zz = mfma16(qf1, kb1, zz);
            sc[nf] = zz;
        }
        if (useMask) {
            #pragma unroll
            for (int nf = 0; nf < 8; ++nf) {
                int kcol = t * 128 + nf * 16 + l15;
                #pragma unroll
                for (int r = 0; r < 4; ++r) {
                    int qrow = qt * 64 + wid * 16 + hi * 4 + r;
                    sc[nf][r] += mask[(size_t)qrow * 2048 + kcol] * 1.4426950408889634f;
                }
            }
        }
        // ---- online softmax (rows = hi*4+r, cols across 16 lanes x 8 frags)
        float tmax[4] = { -1e30f, -1e30f, -1e30f, -1e30f };
        #pragma unroll
        for (int nf = 0; nf < 8; ++nf)
            #pragma unroll
            for (int r = 0; r < 4; ++r) tmax[r] = fmaxf(tmax[r], sc[nf][r]);
        #pragma unroll
        for (int st = 1; st < 16; st <<= 1)
            #pragma unroll
            for (int r = 0; r < 4; ++r) tmax[r] = fmaxf(tmax[r], __shfl_xor(tmax[r], st));
        float mold[4] = { m0r, m1r, m2r, m3r };
        float fac[4], mn[4];
        #pragma unroll
        for (int r = 0; r < 4; ++r) {
            mn[r] = fmaxf(mold[r], tmax[r]);
            fac[r] = exp2f(mold[r] - mn[r]);
        }
        m0r = mn[0]; m1r = mn[1]; m2r = mn[2]; m3r = mn[3];
        float tsum[4] = { 0.f, 0.f, 0.f, 0.f };
        #pragma unroll
        for (int nf = 0; nf < 8; ++nf)
            #pragma unroll
            for (int r = 0; r < 4; ++r) {
                float p = exp2f(sc[nf][r] - mn[r]);
                sc[nf][r] = p;
                tsum[r] += p;
            }
        #pragma unroll
        for (int st = 1; st < 16; st <<= 1)
            #pragma unroll
            for (int r = 0; r < 4; ++r) tsum[r] += __shfl_xor(tsum[r], st);
        l0r = l0r * fac[0] + tsum[0];
        l1r = l1r * fac[1] + tsum[1];
        l2r = l2r * fac[2] + tsum[2];
        l3r = l3r * fac[3] + tsum[3];
        // ---- pack P (bf16) into wave-private swizzled LDS [16 q][128 k]
        #pragma unroll
        for (int nf = 0; nf < 8; ++nf)
            #pragma unroll
            for (int r = 0; r < 4; ++r) {
                int kcol = nf * 16 + l15;
                int qr = hi * 4 + r;
                Pl[wid][qr * 128 + (((kcol >> 3) ^ (qr & 7)) * 8) + (kcol & 7)] = f2bf(sc[nf][r]);
            }
        // ---- fetch this lane's q-column rescale factor and rescale ctx^T
        int r3 = lane & 3;
        float fser = (r3 == 0) ? fac[0] : (r3 == 1) ? fac[1] : (r3 == 2) ? fac[2] : fac[3];
        float facq = __shfl(fser, (l15 >> 2) * 16 + (l15 & 3));
        #pragma unroll
        for (int mi = 0; mi < 4; ++mi) ctxT[mi] *= facq;
        // ---- PV: ctx^T[dk][q] += V^T[dk][k] * P^T[k][q]
        #pragma unroll
        for (int s2 = 0; s2 < 4; ++s2) {
            bf16x8 pb = *(const bf16x8*)&Pl[wid][l15 * 128 + (((s2 * 4 + hi) ^ (l15 & 7)) * 8)];
            #pragma unroll
            for (int mi = 0; mi < 4; ++mi) {
                int vrow = mi * 16 + l15;
                bf16x8 va = *(const bf16x8*)&Vl[vrow * 128 + (((s2 * 4 + hi) ^ (vrow & 7)) * 8)];
                ctxT[mi] = mfma16(va, pb, ctxT[mi]);
            }
        }
        __syncthreads();
    }
    int r3 = lane & 3;
    float lser = (r3 == 0) ? l0r : (r3 == 1) ? l1r : (r3 == 2) ? l2r : l3r;
    float lq = __shfl(lser, (l15 >> 2) * 16 + (l15 & 3));
    float rinv = 1.0f / lq;
    const int b_ = bh >> 4, h_ = bh & 15;
    const size_t obase = ((size_t)b_ * 2048 + qloc) * 1024 + h_ * 64;
    #pragma unroll
    for (int mi = 0; mi < 4; ++mi) {
        bf16x4 o = { f2bf(ctxT[mi][0] * rinv), f2bf(ctxT[mi][1] * rinv),
                     f2bf(ctxT[mi][2] * rinv), f2bf(ctxT[mi][3] * rinv) };
        *(bf16x4*)&ctx[obase + mi * 16 + hi * 4] = o;
    }
}

// -------------------------------------------------------------------- launch
extern "C" void kernel_launch(void* const* d_in, const int* in_sizes, int n_in,
                              void* d_out, int out_size, void* d_ws, size_t ws_size,
                              hipStream_t stream) {
    const float* x     = (const float*)d_in[0];
    const float* mask  = (const float*)d_in[1];
    const float* wq    = (const float*)d_in[2];
    const float* bq    = (const float*)d_in[3];
    const float* wk    = (const float*)d_in[4];
    const float* bk    = (const float*)d_in[5];
    const float* wv    = (const float*)d_in[6];
    const float* bv    = (const float*)d_in[7];
    const float* wo    = (const float*)d_in[8];
    const float* bo    = (const float*)d_in[9];
    const float* w1    = (const float*)d_in[10];
    const float* b1    = (const float*)d_in[11];
    const float* w2    = (const float*)d_in[12];
    const float* b2    = (const float*)d_in[13];
    const float* alpha = (const float*)d_in[14];
    const float* gamma = (const float*)d_in[15];

    char* ws = (char*)d_ws;
    const size_t MB = 1u << 20;
    __bf16* xb    = (__bf16*)(ws + 0 * MB);     // 8M  x bf16 [4096,1024]
    __bf16* qb    = (__bf16*)(ws + 8 * MB);     // 8M  Q [B,H,S,DK] prescaled
    __bf16* kb    = (__bf16*)(ws + 16 * MB);    // 8M  K [B,H,S,DK]
    __bf16* vtb   = (__bf16*)(ws + 24 * MB);    // 8M  V^T [B,H,DK,S]
    __bf16* ctxb  = (__bf16*)(ws + 32 * MB);    // 8M  ctx [B,S,D]
    __bf16* wqb   = (__bf16*)(ws + 40 * MB);    // 2M
    __bf16* wkb   = (__bf16*)(ws + 42 * MB);    // 2M
    __bf16* wvb   = (__bf16*)(ws + 44 * MB);    // 2M
    __bf16* wob   = (__bf16*)(ws + 46 * MB);    // 2M
    __bf16* w1b   = (__bf16*)(ws + 48 * MB);    // 8M
    __bf16* w2b   = (__bf16*)(ws + 56 * MB);    // 8M
    float*  attn  = (float*)(ws + 64 * MB);     // 16M (reused for ffn out)
    float*  out1  = (float*)(ws + 80 * MB);     // 16M
    __bf16* out1b = (__bf16*)(ws + 96 * MB);    // 8M
    __bf16* hid   = (__bf16*)(ws + 104 * MB);   // 32M [4096,4096]
    int*    mflag = (int*)(ws + 136 * MB);
    if (ws_size < 136 * MB + 64) return;  // workspace too small -> loud failure

    init_flag_kernel<<<1, 1, 0, stream>>>(mflag);
    mask_scan_kernel<<<2048, 256, 0, stream>>>(mask, mflag);

    cast_bf16_kernel<<<2048, 256, 0, stream>>>(x, xb, 524288);
    cast_bf16_kernel<<<512, 256, 0, stream>>>(wq, wqb, 131072);
    cast_bf16_kernel<<<512, 256, 0, stream>>>(wk, wkb, 131072);
    cast_bf16_kernel<<<512, 256, 0, stream>>>(wv, wvb, 131072);
    cast_bf16_kernel<<<512, 256, 0, stream>>>(wo, wob, 131072);
    cast_bf16_kernel<<<2048, 256, 0, stream>>>(w1, w1b, 524288);
    cast_bf16_kernel<<<2048, 256, 0, stream>>>(w2, w2b, 524288);

    gemm_qkv_kernel<<<dim3(8, 32, 3), 256, 0, stream>>>(xb, wqb, wkb, wvb, bq, bk, bv,
                                                        qb, kb, vtb);
    flash_attn_kernel<<<dim3(32, 32), 256, 0, stream>>>(qb, kb, vtb, mask, mflag, ctxb);
    gemm_bt_kernel<1024, 1024, 64, 0><<<dim3(16, 32), 256, 0, stream>>>(ctxb, wob, bo, attn);
    add_ln_kernel<<<4096, 256, 0, stream>>>(x, attn, alpha, gamma, out1, out1b);
    gemm_bt_kernel<4096, 1024, 128, 1><<<dim3(32, 32), 256, 0, stream>>>(out1b, w1b, b1, hid);
    gemm_bt_kernel<1024, 4096, 64, 0><<<dim3(16, 32), 256, 0, stream>>>(hid, w2b, b2, attn);
    add_ln_kernel<<<4096, 256, 0, stream>>>(out1, attn, alpha, gamma, (float*)d_out, nullptr);
}